// Round 6
// baseline (478.170 us; speedup 1.0000x reference)
//
#include <hip/hip_runtime.h>
#include <stdint.h>

// KronQRInjectedLinear: out = ((input @ rot) @ Q) @ R_eff.
// Kron structure: D via 4x2048^3 batched, rot via 2x4096x2048x2048 (see r4).
// GEMM core v4: 256x256 tile, 8 waves (2Mx4N), BK=32 chunks in 4 rotating
// 32KB buffers (A 16K + B 16K each), uniform 4-5-phase prefetch distance,
// vmcnt(8) twice per 4-phase iter (2 chunks always in flight), zero-conflict
// XOR swizzle, setprio, XCD swizzle.

typedef unsigned short u16;
typedef short bf16x8 __attribute__((ext_vector_type(8)));
typedef float f32x4 __attribute__((ext_vector_type(4)));

__device__ __forceinline__ u16 f2bf(float f) {
  union { float f; uint32_t u; } v; v.f = f;
  return (u16)((v.u + 0x7FFFu + ((v.u >> 16) & 1u)) >> 16);
}

__device__ __forceinline__ void store_out(float* p, float v) { *p = v; }
__device__ __forceinline__ void store_out(u16* p, float v) { *p = f2bf(v); }

__device__ __forceinline__ void gload_lds16(const u16* g, u16* l) {
  __builtin_amdgcn_global_load_lds(
      (__attribute__((address_space(1))) void*)(uintptr_t)g,
      (__attribute__((address_space(3))) void*)l, 16, 0, 0);
}

#define MFMA16(a, b, c) __builtin_amdgcn_mfma_f32_16x16x32_bf16((a), (b), (c), 0, 0, 0)

// ---------------- GEMM: C[M,N] = A[M,K] @ Bt[N,K]^T (batched on z) ----------------
// Chunk (BK=32) = 2 pieces (rh=0,1) of 8KB each per matrix. Piece layout, elem (rp,kk):
//   (rp>>1)*64 + ((((kk>>3)+4*(rp&1)) ^ ((rp>>1)&7))*8) + (kk&7)
// 4 chunk-buffers per matrix: chunk c -> buf c&3. LDS total 128 KB.
template <typename OutT>
__global__ __launch_bounds__(512, 2) void gemm256(
    const u16* __restrict__ A, const u16* __restrict__ Bt, OutT* __restrict__ C,
    int M, int N, int K, int ldC, long long sA, long long sC) {
  extern __shared__ __align__(16) u16 smem[];
  u16* ldsA = smem;           // 4 bufs x 8192 elems (64 KB)
  u16* ldsB = smem + 32768;

  const int tid  = (int)threadIdx.x;
  const int lane = tid & 63;
  const int wid  = tid >> 6;
  const int wr   = wid >> 2;       // 0..1 : M half (128 rows)
  const int wc   = wid & 3;        // 0..3 : N quarter (64 cols)

  // XCD-aware bijective swizzle (nwg % 8 == 0 for all our grids)
  const int tilesX = (int)gridDim.x;
  const int tilesXY = tilesX * (int)gridDim.y;
  const int nwg = tilesXY * (int)gridDim.z;
  const int bid = ((int)blockIdx.z * (int)gridDim.y + (int)blockIdx.y) * tilesX + (int)blockIdx.x;
  const int swz = (bid & 7) * (nwg >> 3) + (bid >> 3);
  const int z   = swz / tilesXY;
  const int rem = swz % tilesXY;
  const int brow = (rem / tilesX) << 8;
  const int bcol = (rem % tilesX) << 8;
  A += (size_t)z * sA;
  C += (size_t)z * sC;

  // fragment-read lane constants (swizzled 16B slot is lane-constant)
  const int lr = lane & 15, lg = lane >> 4, h = lr >> 1;
  const int sf = (lg + ((lr & 1) << 2)) ^ h;
  const int abase = wr * 4096 + h * 64 + sf * 8;                     // + m*512, + buf*8192
  const int bbase = (wc >> 1) * 4096 + (wc & 1) * 2048 + h * 64 + sf * 8;  // + n*512

  // staging: linear LDS dest (tid*16B within 8KB piece), inverse-swizzled source
  const int kp   = (tid & 7) ^ ((tid >> 3) & 7);
  const int srow = 2 * (tid >> 3) + (kp >> 2);
  const int scol = (kp & 3) << 3;
  const size_t gA0 = (size_t)(brow + srow) * K + scol;
  const size_t gB0 = (size_t)(bcol + srow) * K + scol;
  const size_t rstep = (size_t)K << 7;     // 128 rows
  const int sdst = wid * 512;

  const int NC = K >> 5;                   // 32-wide chunks; NC % 4 == 0, NC >= 8

  f32x4 acc[8][4] = {};
  bf16x8 af[8], bf[4];

#define STG_A(c, rh) gload_lds16(A + gA0 + (rh) * rstep + (size_t)(c) * 32, \
    ldsA + ((c) & 3) * 8192 + (rh) * 4096 + sdst)
#define STG_B(c, rh) gload_lds16(Bt + gB0 + (rh) * rstep + (size_t)(c) * 32, \
    ldsB + ((c) & 3) * 8192 + (rh) * 4096 + sdst)
#define VM8 asm volatile("s_waitcnt vmcnt(8)" ::: "memory")
#define VM4 asm volatile("s_waitcnt vmcnt(4)" ::: "memory")
#define VM0 asm volatile("s_waitcnt vmcnt(0)" ::: "memory")
#define NOPW (void)0

  // Even phase of chunk in buf bb: read af0-3 + bf0-3, stage S, MFMA m0-3 x n0-3.
#define P_EVEN(bb, S, W) do {                                                   \
    const u16* _pa = ldsA + (bb) * 8192 + abase;                                \
    const u16* _pb = ldsB + (bb) * 8192 + bbase;                                \
    _Pragma("unroll")                                                           \
    for (int m = 0; m < 4; ++m) af[m] = *(const bf16x8*)(_pa + m * 512);        \
    _Pragma("unroll")                                                           \
    for (int n = 0; n < 4; ++n) bf[n] = *(const bf16x8*)(_pb + n * 512);        \
    S;                                                                          \
    __builtin_amdgcn_s_barrier();                                               \
    asm volatile("s_waitcnt lgkmcnt(0)" ::: "memory");                          \
    __builtin_amdgcn_sched_barrier(0);                                          \
    __builtin_amdgcn_s_setprio(1);                                              \
    _Pragma("unroll")                                                           \
    for (int m = 0; m < 4; ++m)                                                 \
      _Pragma("unroll")                                                         \
      for (int n = 0; n < 4; ++n)                                               \
        acc[m][n] = MFMA16(af[m], bf[n], acc[m][n]);                            \
    __builtin_amdgcn_s_setprio(0);                                              \
    W;                                                                          \
    __builtin_amdgcn_sched_barrier(0);                                          \
    __builtin_amdgcn_s_barrier();                                               \
  } while (0)

  // Odd phase: read af4-7 (bf persists), MFMA m4-7 x n0-3.
#define P_ODD(bb, S, W) do {                                                    \
    const u16* _pa = ldsA + (bb) * 8192 + abase;                                \
    _Pragma("unroll")                                                           \
    for (int m = 0; m < 4; ++m) af[4 + m] = *(const bf16x8*)(_pa + (4 + m) * 512); \
    S;                                                                          \
    __builtin_amdgcn_s_barrier();                                               \
    asm volatile("s_waitcnt lgkmcnt(0)" ::: "memory");                          \
    __builtin_amdgcn_sched_barrier(0);                                          \
    __builtin_amdgcn_s_setprio(1);                                              \
    _Pragma("unroll")                                                           \
    for (int m = 0; m < 4; ++m)                                                 \
      _Pragma("unroll")                                                         \
      for (int n = 0; n < 4; ++n)                                               \
        acc[4 + m][n] = MFMA16(af[4 + m], bf[n], acc[4 + m][n]);                \
    __builtin_amdgcn_s_setprio(0);                                              \
    W;                                                                          \
    __builtin_amdgcn_sched_barrier(0);                                          \
    __builtin_amdgcn_s_barrier();                                               \
  } while (0)

  // Iter: compute chunks c (buf bb), c+1 (buf bb+1); stage c+3 (buf bb^3) @p0-1,
  // c+4 (buf bb) @p2-3. Issue->need distance 4-5 phases for every piece; waits
  // vmcnt(8) keep 2 chunks (8 loads) in flight.
#define ITER(bb, c, DO3, DO4, W1, W3) do {                                      \
    P_EVEN((bb),     if (DO3) { STG_A((c) + 3, 0); STG_A((c) + 3, 1); }, NOPW); \
    P_ODD ((bb),     if (DO3) { STG_B((c) + 3, 0); STG_B((c) + 3, 1); }, W1);   \
    P_EVEN((bb) + 1, if (DO4) { STG_A((c) + 4, 0); STG_A((c) + 4, 1); }, NOPW); \
    P_ODD ((bb) + 1, if (DO4) { STG_B((c) + 4, 0); STG_B((c) + 4, 1); }, W3);   \
  } while (0)

  // Prologue: chunks 0,1,2 staged; complete chunk 0, leave 1,2 (8 loads) in flight.
  STG_A(0, 0); STG_A(0, 1); STG_B(0, 0); STG_B(0, 1);
  STG_A(1, 0); STG_A(1, 1); STG_B(1, 0); STG_B(1, 1);
  STG_A(2, 0); STG_A(2, 1); STG_B(2, 0); STG_B(2, 1);
  VM8;
  __builtin_amdgcn_sched_barrier(0);
  __builtin_amdgcn_s_barrier();

  for (int c = 0; c + 4 < NC; c += 4) {
    ITER(0, c,     1, 1, VM8, VM8);
    ITER(2, c + 2, 1, 1, VM8, VM8);
  }
  ITER(0, NC - 4, 1, 0, VM8, VM4);   // stages only chunk NC-1
  ITER(2, NC - 2, 0, 0, VM0, NOPW);

#undef ITER
#undef P_EVEN
#undef P_ODD
#undef STG_A
#undef STG_B
#undef VM8
#undef VM4
#undef VM0
#undef NOPW

  // C/D layout per 16x16 frag: col = lane&15, row = (lane>>4)*4 + j
#pragma unroll
  for (int m = 0; m < 8; ++m) {
    const int r0 = brow + wr * 128 + m * 16 + lg * 4;
#pragma unroll
    for (int n = 0; n < 4; ++n) {
      const int cc = bcol + wc * 64 + n * 16 + lr;
#pragma unroll
      for (int j = 0; j < 4; ++j)
        store_out(&C[(size_t)(r0 + j) * ldC + cc], acc[m][n][j]);
    }
  }
}

// ---------------- tiled transpose: out[c][r] = bf16(in[r][c]) ----------------
__global__ void trans_kernel(const float* __restrict__ in, u16* __restrict__ out, int n) {
  __shared__ float t[32][33];
  const int bx = (int)blockIdx.x * 32, by = (int)blockIdx.y * 32;
  const int x = (int)threadIdx.x, y0 = (int)threadIdx.y;
#pragma unroll
  for (int dy = 0; dy < 32; dy += 8)
    t[y0 + dy][x] = in[(size_t)(bx + y0 + dy) * n + by + x];
  __syncthreads();
#pragma unroll
  for (int dy = 0; dy < 32; dy += 8)
    out[(size_t)(by + y0 + dy) * n + bx + x] = f2bf(t[x][y0 + dy]);
}

// Qtp[c][perm(r)] = bf16(Q[r][c]); perm(r) = ((r&1)<<11)|(r>>1)
__global__ void transperm_kernel(const float* __restrict__ in, u16* __restrict__ out) {
  __shared__ float t[32][33];
  const int bx = (int)blockIdx.x * 32, by = (int)blockIdx.y * 32;
  const int x = (int)threadIdx.x, y0 = (int)threadIdx.y;
#pragma unroll
  for (int dy = 0; dy < 32; dy += 8)
    t[y0 + dy][x] = in[(size_t)(bx + y0 + dy) * 4096 + by + x];
  __syncthreads();
  const int r = bx + x;
  const int cp = ((r & 1) << 11) | (r >> 1);
#pragma unroll
  for (int dy = 0; dy < 32; dy += 8)
    out[(size_t)(by + y0 + dy) * 4096 + cp] = f2bf(t[x][y0 + dy]);
}

// rteff[i][j] = bf16(R[j][i] + D[i][j]); D[i][j] = Dsub[(i&1)*2+(j&1)][i>>1][j>>1]
__global__ void transadd_kernel(const float* __restrict__ R, const float* __restrict__ Dsub,
                                u16* __restrict__ out) {
  __shared__ float t[32][33];
  const int bx = (int)blockIdx.x * 32, by = (int)blockIdx.y * 32;
  const int x = (int)threadIdx.x, y0 = (int)threadIdx.y;
#pragma unroll
  for (int dy = 0; dy < 32; dy += 8)
    t[y0 + dy][x] = R[(size_t)(bx + y0 + dy) * 4096 + by + x];
  __syncthreads();
  const int j = bx + x;
#pragma unroll
  for (int dy = 0; dy < 32; dy += 8) {
    const int i = by + y0 + dy;
    const int s = ((i & 1) << 1) | (j & 1);
    const float d = Dsub[(size_t)s * 4194304 + ((size_t)(i >> 1) << 11) + (j >> 1)];
    out[(size_t)i * 4096 + j] = f2bf(t[x][y0 + dy] + d);
  }
}

// R1bf = bf16(R1); Asc[s][i1][k1] = bf16(R1[i1][k1] * g_s[k1])
__global__ void scale_r1_kernel(const float* __restrict__ R1, const float* __restrict__ R2,
                                const float* __restrict__ lam,
                                u16* __restrict__ R1bf, u16* __restrict__ Asc) {
  const int idx = (int)blockIdx.x * 256 + (int)threadIdx.x;   // over 2048*512
  const int i1 = idx >> 9, k1 = (idx & 511) << 2;
  const float4 r1 = *(const float4*)(R1 + (size_t)i1 * 2048 + k1);
  const float4 l0 = *(const float4*)(lam + 2 * k1);
  const float4 l1 = *(const float4*)(lam + 2 * k1 + 4);
  const float le[4] = {l0.x, l0.z, l1.x, l1.z};
  const float lo[4] = {l0.y, l0.w, l1.y, l1.w};
  const float rv[4] = {r1.x, r1.y, r1.z, r1.w};
  ushort4 rb;
  rb.x = f2bf(r1.x); rb.y = f2bf(r1.y); rb.z = f2bf(r1.z); rb.w = f2bf(r1.w);
  *(ushort4*)(R1bf + (size_t)i1 * 2048 + k1) = rb;
#pragma unroll
  for (int s = 0; s < 4; ++s) {
    const int i2 = s >> 1, j2 = s & 1;
    const float c0 = R2[i2 * 2] * R2[j2 * 2];
    const float c1 = R2[i2 * 2 + 1] * R2[j2 * 2 + 1];
    ushort4 o;
    u16* dst = Asc + (size_t)s * 4194304 + (size_t)i1 * 2048 + k1;
    o.x = f2bf(rv[0] * (le[0] * c0 + lo[0] * c1));
    o.y = f2bf(rv[1] * (le[1] * c0 + lo[1] * c1));
    o.z = f2bf(rv[2] * (le[2] * c0 + lo[2] * c1));
    o.w = f2bf(rv[3] * (le[3] * c0 + lo[3] * c1));
    *(ushort4*)dst = o;
  }
}

// T[j2][s][k1] = bf16(in[s][2k1]*Q2[0][j2] + in[s][2k1+1]*Q2[1][j2])
__global__ void tprep_kernel(const float* __restrict__ in, const float* __restrict__ Q2,
                             u16* __restrict__ T) {
  const int idx = (int)blockIdx.x * 256 + (int)threadIdx.x;   // over 4096*512
  const int s = idx >> 9, k1 = (idx & 511) << 2;
  const float4 a = *(const float4*)(in + (size_t)s * 4096 + 2 * k1);
  const float4 b = *(const float4*)(in + (size_t)s * 4096 + 2 * k1 + 4);
  const float e[4] = {a.x, a.z, b.x, b.z};
  const float o[4] = {a.y, a.w, b.y, b.w};
  const float q00 = Q2[0], q01 = Q2[1], q10 = Q2[2], q11 = Q2[3];
  ushort4 t0, t1;
  t0.x = f2bf(e[0] * q00 + o[0] * q10); t1.x = f2bf(e[0] * q01 + o[0] * q11);
  t0.y = f2bf(e[1] * q00 + o[1] * q10); t1.y = f2bf(e[1] * q01 + o[1] * q11);
  t0.z = f2bf(e[2] * q00 + o[2] * q10); t1.z = f2bf(e[2] * q01 + o[2] * q11);
  t0.w = f2bf(e[3] * q00 + o[3] * q10); t1.w = f2bf(e[3] * q01 + o[3] * q11);
  *(ushort4*)(T + (size_t)s * 2048 + k1) = t0;
  *(ushort4*)(T + 8388608 + (size_t)s * 2048 + k1) = t1;
}

extern "C" void kernel_launch(void* const* d_in, const int* in_sizes, int n_in,
                              void* d_out, int out_size, void* d_ws, size_t ws_size,
                              hipStream_t stream) {
  const float* input = (const float*)d_in[0];
  const float* Q     = (const float*)d_in[1];
  const float* R     = (const float*)d_in[2];
  const float* Q1    = (const float*)d_in[3];
  const float* Q2    = (const float*)d_in[4];
  const float* R1    = (const float*)d_in[5];
  const float* R2    = (const float*)d_in[6];
  const float* lam   = (const float*)d_in[7];
  float* out = (float*)d_out;

  const size_t MB = 1024ull * 1024ull;
  char* ws = (char*)d_ws;
  u16* R1bf  = (u16*)(ws + 0 * MB);
  u16* Asc   = (u16*)(ws + 8 * MB);     // 4 planes of 8MB; reused as X2 later
  u16* Q1tb  = (u16*)(ws + 40 * MB);
  u16* T     = (u16*)(ws + 48 * MB);    // 2 planes of 16MB
  u16* Qtp   = (u16*)(ws + 80 * MB);
  u16* rteff = (u16*)(ws + 112 * MB);
  u16* X1p   = (u16*)(ws + 144 * MB);   // needs ws_size >= 176 MB
  u16* X2    = Asc;
  float* Dsub = (float*)d_out;          // 4 x 2048^2 f32, consumed by transadd

  {
    void (*pf)(const u16*, const u16*, float*, int, int, int, int, long long, long long) = gemm256<float>;
    void (*pb)(const u16*, const u16*, u16*, int, int, int, int, long long, long long)   = gemm256<u16>;
    (void)hipFuncSetAttribute((const void*)pf, hipFuncAttributeMaxDynamicSharedMemorySize, 131072);
    (void)hipFuncSetAttribute((const void*)pb, hipFuncAttributeMaxDynamicSharedMemorySize, 131072);
  }

  const dim3 tb(32, 8);
  // 1) Q1tb = bf16(Q1^T)
  trans_kernel<<<dim3(64, 64), tb, 0, stream>>>(Q1, Q1tb, 2048);
  // 2) Qtp = permuted bf16(Q^T)
  transperm_kernel<<<dim3(128, 128), tb, 0, stream>>>(Q, Qtp);
  // 3) R1bf + scaled copies Asc[s]
  scale_r1_kernel<<<4096, 256, 0, stream>>>(R1, R2, lam, R1bf, Asc);
  // 4) T[j2] = Q2-contraction of input
  tprep_kernel<<<8192, 256, 0, stream>>>(input, Q2, T);
  // 5) Dsub[s] = Asc[s] @ R1bf^T   (batched 4 x 2048^3)
  gemm256<float><<<dim3(8, 8, 4), 512, 131072, stream>>>(
      Asc, R1bf, Dsub, 2048, 2048, 2048, 2048, 4194304LL, 4194304LL);
  // 6) rteff = R^T + D
  transadd_kernel<<<dim3(128, 128), tb, 0, stream>>>(R, Dsub, rteff);
  // 7) X1p[:, j2*2048+j1] = T[j2] @ Q1tb^T   (batched 2 x 4096x2048x2048)
  gemm256<u16><<<dim3(8, 16, 2), 512, 131072, stream>>>(
      T, Q1tb, X1p, 4096, 2048, 2048, 4096, 8388608LL, 2048LL);
  // 8) X2 = X1p @ Qtp^T   (4096^3)
  gemm256<u16><<<dim3(16, 16, 1), 512, 131072, stream>>>(
      X1p, Qtp, X2, 4096, 4096, 4096, 4096, 0LL, 0LL);
  // 9) out = X2 @ rteff^T  (4096^3, f32)
  gemm256<float><<<dim3(16, 16, 1), 512, 131072, stream>>>(
      X2, rteff, out, 4096, 4096, 4096, 4096, 0LL, 0LL);
}